// Round 9
// baseline (357.774 us; speedup 1.0000x reference)
//
#include <hip/hip_runtime.h>
#include <math.h>

#define B_ 4
#define T_ 1024
#define D_ 2048
#define NH 16
#define NKV 4
#define HD 128
#define KV_D 512    // NKV * HD
#define QKV_S 2560  // QKV row stride: Q (2048) + K (512); V goes only to Vt

typedef __attribute__((ext_vector_type(8))) short short8;   // 8 x bf16 (4 VGPRs)
typedef __attribute__((ext_vector_type(4))) float f32x4;    // MFMA accumulator

// fp32 -> bf16 round-to-nearest-even (finite inputs)
__device__ __forceinline__ ushort f2b(float f) {
    unsigned u = __float_as_uint(f);
    return (ushort)((u + 0x7fffu + ((u >> 16) & 1u)) >> 16);
}
__device__ __forceinline__ float b2f(ushort u) {
    return __uint_as_float((unsigned)u << 16);
}

// exp2 via v_exp_f32 (no hidden log2e multiply like __expf)
#if __has_builtin(__builtin_amdgcn_exp2f)
#define EXP2F(x) __builtin_amdgcn_exp2f(x)
#else
#define EXP2F(x) __expf((x) * 0.6931471805599453f)
#endif

#define ASYNC_COPY16(g, l)                                                  \
    __builtin_amdgcn_global_load_lds(                                       \
        (const __attribute__((address_space(1))) void*)(g),                 \
        (__attribute__((address_space(3))) void*)(l), 16, 0, 0)

#define MFMA16(ap, bp, cc) cc = __builtin_amdgcn_mfma_f32_16x16x32_bf16(ap, bp, cc, 0, 0, 0)

// ---------------------------------------------------------------------------
// prep_all (round-6 verified, vectorized transposes): 6 jobs by bid range:
//   [0,8192)       cast x fp32 -> bf16 (float4 per thread)
//   [8192,9216)    Wq -> WqkvT rows 0..2047      (64x64 vectorized transpose)
//   [9216,9472)    Wk -> WqkvT rows 2048..2559
//   [9472,9728)    Wv -> WqkvT rows 2560..3071
//   [9728,10752)   Wo -> WoT
//   [10752,11008)  rope table: tab[t*64+i] = {cos, sin}(t * 10000^(-i/64))
// ---------------------------------------------------------------------------
__global__ __launch_bounds__(256) void prep_all(const float* __restrict__ x,
                                                const float* __restrict__ Wq,
                                                const float* __restrict__ Wk,
                                                const float* __restrict__ Wv,
                                                const float* __restrict__ Wo,
                                                ushort* __restrict__ xb,
                                                ushort* __restrict__ WqkvT,
                                                ushort* __restrict__ WoT,
                                                float2* __restrict__ tab) {
    __shared__ float tile[64][65];
    const int bid = blockIdx.x;
    const int tid = threadIdx.x;
    if (bid < 8192) {                      // cast job
        const int i = bid * 256 + tid;
        const float4 v = ((const float4*)x)[i];
        ushort4 u;
        u.x = f2b(v.x); u.y = f2b(v.y); u.z = f2b(v.z); u.w = f2b(v.w);
        ((ushort4*)xb)[i] = u;
        return;
    }
    if (bid >= 10752) {                    // rope table job
        const int idx = (bid - 10752) * 256 + tid;
        const int t = idx >> 6, i = idx & 63;
        const float inv = exp2f((float)i * (-13.287712379549449f / 64.0f));
        const float ang = (float)t * inv;
        tab[idx] = make_float2(cosf(ang), sinf(ang));
        return;
    }
    // transpose jobs: W [2048][N] fp32 -> WT [N][2048] bf16, 64x64 tiles
    const float* W;
    ushort* WT;
    int N, rb;
    if (bid < 9216)      { W = Wq; WT = WqkvT;                           N = D_;   rb = bid - 8192; }
    else if (bid < 9472) { W = Wk; WT = WqkvT + (size_t)D_ * D_;         N = KV_D; rb = bid - 9216; }
    else if (bid < 9728) { W = Wv; WT = WqkvT + (size_t)(D_+KV_D) * D_;  N = KV_D; rb = bid - 9472; }
    else                 { W = Wo; WT = WoT;                             N = D_;   rb = bid - 9728; }
    const int bxn = N / 64;
    const int n0 = (rb % bxn) * 64, k0 = (rb / bxn) * 64;
    // load 64x64 floats: 16 lanes x float4 = 256 B contiguous per row
    const int tx = tid & 15, ty = tid >> 4;
#pragma unroll
    for (int i = 0; i < 4; ++i) {
        const int r = ty + i * 16;
        const float4 v = *(const float4*)&W[(size_t)(k0 + r) * N + n0 + tx * 4];
        tile[r][tx * 4 + 0] = v.x;
        tile[r][tx * 4 + 1] = v.y;
        tile[r][tx * 4 + 2] = v.z;
        tile[r][tx * 4 + 3] = v.w;
    }
    __syncthreads();
    // write: output row n = tid>>2 (4 lanes/row -> 128 B contiguous segments)
    const int n = tid >> 2, ch = (tid & 3) * 16;
    ushort tmp[16];
#pragma unroll
    for (int j = 0; j < 16; ++j) tmp[j] = f2b(tile[ch + j][n]);
    ushort* orow = WT + (size_t)(n0 + n) * D_ + k0 + ch;
    *(short8*)&orow[0] = *(short8*)&tmp[0];
    *(short8*)&orow[8] = *(short8*)&tmp[8];
}

// ---------------------------------------------------------------------------
// Fused QKV projection GEMM (round-0 verified, 76.6 us): C = xb x WqkvT^T,
// 128x128 tile, m97 K-loop (BK=32, global_load_lds width-16), per-head
// epilogue: Q/K rope via table, V transpose to Vt. LDS = 34816 B.
// ---------------------------------------------------------------------------
__global__ __launch_bounds__(256) void gemm_qkv(const ushort* __restrict__ A,
                                                const ushort* __restrict__ BT,
                                                ushort* __restrict__ QKV,
                                                ushort* __restrict__ Vt,
                                                const float2* __restrict__ tab) {
    __shared__ ushort smem[128 * 136];     // 34816 B; staging aliases the front
    ushort* As = smem;                     // 128*32 = 4096 ushorts
    ushort* Bs = smem + 4096;
    const int K = D_;
    const int tid = threadIdx.x;
    const int m0 = blockIdx.y * 128, n0 = blockIdx.x * 128;
    const int hid = n0 >> 7;               // 0..23
    const int wave = tid >> 6, lane = tid & 63;
    const int wm = (wave >> 1) * 64, wn = (wave & 1) * 64;
    const int lrow = lane & 15;
    const int quad = lane >> 4;

    f32x4 acc[4][4];
    const f32x4 zero = {0.f, 0.f, 0.f, 0.f};
#pragma unroll
    for (int i = 0; i < 4; ++i)
#pragma unroll
        for (int j = 0; j < 4; ++j) acc[i][j] = zero;

    const int srow = tid >> 2;
    const int scol = (tid & 3) * 8;
    const ushort* Ag = A + (size_t)(m0 + srow) * K + scol;
    const ushort* Bg = BT + (size_t)(n0 + srow) * K + scol;
    ushort* AsT = As + tid * 8;
    ushort* BsT = Bs + tid * 8;

    for (int k0 = 0; k0 < K; k0 += 32) {
        ASYNC_COPY16(Ag + k0, AsT);
        ASYNC_COPY16(Ag + k0 + (size_t)64 * K, AsT + 64 * 32);
        ASYNC_COPY16(Bg + k0, BsT);
        ASYNC_COPY16(Bg + k0 + (size_t)64 * K, BsT + 64 * 32);
        __syncthreads();

        short8 a[4], b[4];
#pragma unroll
        for (int mt = 0; mt < 4; ++mt)
            a[mt] = *(const short8*)&As[(wm + mt * 16 + lrow) * 32 + quad * 8];
#pragma unroll
        for (int nt = 0; nt < 4; ++nt)
            b[nt] = *(const short8*)&Bs[(wn + nt * 16 + lrow) * 32 + quad * 8];
#pragma unroll
        for (int mt = 0; mt < 4; ++mt)
#pragma unroll
            for (int nt = 0; nt < 4; ++nt)
                acc[mt][nt] = __builtin_amdgcn_mfma_f32_16x16x32_bf16(
                    a[mt], b[nt], acc[mt][nt], 0, 0, 0);
        __syncthreads();   // also guarantees staging LDS is dead -> Epi reuse
    }

    // ---- epilogue: acc (C-layout) -> bf16 LDS tile Epi[128 t][136 d-pad] ----
    ushort* Epi = smem;
#pragma unroll
    for (int mt = 0; mt < 4; ++mt)
#pragma unroll
        for (int nt = 0; nt < 4; ++nt)
#pragma unroll
            for (int r = 0; r < 4; ++r)
                Epi[(wm + mt * 16 + quad * 4 + r) * 136 + wn + nt * 16 + lrow] =
                    f2b(acc[mt][nt][r]);
    __syncthreads();

    const int b = m0 >> 10;        // batch (tile rows share one batch)
    const int t0 = m0 & 1023;

    if (hid < NH + NKV) {
        // ---- Q or K head: rope from table, write to QKV ----
        const bool isQ = hid < NH;
        const size_t colbase = isQ ? hid * HD : (size_t)D_ + (hid - NH) * HD;
        // Q scale: 1/sqrt(128) * log2(e) (softmax runs in exp2 domain)
        const float sc = isQ ? (0.08838834764831845f * 1.4426950408889634f) : 1.0f;
        const int r = tid >> 1;            // local t row 0..127
        const int hf = tid & 1;            // d-half group: d in [hf*32, hf*32+32)
        const int t = t0 + r;
        ushort* orow = QKV + (size_t)(m0 + r) * QKV_S + colbase;
        const float4* tab4 = (const float4*)tab;   // 2 (cos,sin) pairs per float4
#pragma unroll
        for (int jj = 0; jj < 4; ++jj) {
            const int dbase = hf * 32 + jj * 8;
            const short8 lo = *(const short8*)&Epi[r * 136 + dbase];
            const short8 hi = *(const short8*)&Epi[r * 136 + 64 + dbase];
            ushort olo[8], ohi[8];
#pragma unroll
            for (int k = 0; k < 4; ++k) {
                const float4 cs = tab4[((t * 64 + dbase) >> 1) + k];
                const float x1a = b2f(lo[2 * k]),     x2a = b2f(hi[2 * k]);
                const float x1b = b2f(lo[2 * k + 1]), x2b = b2f(hi[2 * k + 1]);
                olo[2 * k]     = f2b((x1a * cs.x - x2a * cs.y) * sc);
                ohi[2 * k]     = f2b((x2a * cs.x + x1a * cs.y) * sc);
                olo[2 * k + 1] = f2b((x1b * cs.z - x2b * cs.w) * sc);
                ohi[2 * k + 1] = f2b((x2b * cs.z + x1b * cs.w) * sc);
            }
            *(short8*)&orow[dbase]      = *(short8*)olo;
            *(short8*)&orow[dbase + 64] = *(short8*)ohi;
        }
    } else {
        // ---- V head: transpose Epi[t][d] -> Vt[(b*NKV+kv)*HD + d][t] ----
        const int kv = hid - (NH + NKV);
        const int d = tid & 127;           // conflict-free column reads (2-way)
        const int hf = tid >> 7;           // t-half: [hf*64, hf*64+64)
        ushort* vrow = Vt + ((size_t)((b * NKV + kv) * HD + d)) * T_ + t0 + hf * 64;
#pragma unroll
        for (int jj = 0; jj < 8; ++jj) {
            ushort pk[8];
#pragma unroll
            for (int k = 0; k < 8; ++k)
                pk[k] = Epi[(hf * 64 + jj * 8 + k) * 136 + d];
            *(short8*)&vrow[jj * 8] = *(short8*)pk;
        }
    }
}

// ---------------------------------------------------------------------------
// Output-projection GEMM (round-8 verified): BK=64 + swizzle variant.
// C[M,N] fp32 = A[M,K] bf16 x BT[N,K] bf16.
// ---------------------------------------------------------------------------
__global__ __launch_bounds__(256) void gemm_bf16(const ushort* __restrict__ A,
                                                 const ushort* __restrict__ BT,
                                                 float* __restrict__ C,
                                                 int M, int N, int K) {
    __shared__ ushort As[128 * 64];
    __shared__ ushort Bs[128 * 64];
    const int tid = threadIdx.x;
    const int m0 = blockIdx.y * 128, n0 = blockIdx.x * 128;
    const int wave = tid >> 6, lane = tid & 63;
    const int wm = (wave >> 1) * 64, wn = (wave & 1) * 64;
    const int lrow = lane & 15;
    const int quad = lane >> 4;

    f32x4 acc[4][4];
    const f32x4 zero = {0.f, 0.f, 0.f, 0.f};
#pragma unroll
    for (int i = 0; i < 4; ++i)
#pragma unroll
        for (int j = 0; j < 4; ++j) acc[i][j] = zero;

    const int srow = tid >> 3;
    const int scol = ((tid & 7) * 8) ^ ((srow & 7) << 3);   // pre-swizzled src col
    const ushort* Ag = A + (size_t)(m0 + srow) * K + scol;
    const ushort* Bg = BT + (size_t)(n0 + srow) * K + scol;
    ushort* AsT = As + tid * 8;
    ushort* BsT = Bs + tid * 8;
    const int swr = (lrow & 7) << 3;       // read-side un-swizzle

    for (int k0 = 0; k0 < K; k0 += 64) {
#pragma unroll
        for (int c = 0; c < 4; ++c) {
            ASYNC_COPY16(Ag + k0 + (size_t)(c * 32) * K, AsT + c * 2048);
            ASYNC_COPY16(Bg + k0 + (size_t)(c * 32) * K, BsT + c * 2048);
        }
        __syncthreads();

#pragma unroll
        for (int ks = 0; ks < 2; ++ks) {
            const int col = (quad * 8) ^ (ks * 32) ^ swr;
            short8 a[4], b[4];
#pragma unroll
            for (int mt = 0; mt < 4; ++mt)
                a[mt] = *(const short8*)&As[(wm + mt * 16 + lrow) * 64 + col];
#pragma unroll
            for (int nt = 0; nt < 4; ++nt)
                b[nt] = *(const short8*)&Bs[(wn + nt * 16 + lrow) * 64 + col];
#pragma unroll
            for (int mt = 0; mt < 4; ++mt)
#pragma unroll
                for (int nt = 0; nt < 4; ++nt)
                    MFMA16(a[mt], b[nt], acc[mt][nt]);
        }
        __syncthreads();
    }

    const int crow = quad * 4;
    const int ccol = lrow;
#pragma unroll
    for (int mt = 0; mt < 4; ++mt)
#pragma unroll
        for (int nt = 0; nt < 4; ++nt)
#pragma unroll
            for (int r = 0; r < 4; ++r)
                C[(size_t)(m0 + wm + mt * 16 + crow + r) * N +
                  n0 + wn + nt * 16 + ccol] = acc[mt][nt][r];
}

// ---------------------------------------------------------------------------
// MFMA flash attention, round-9: 128 q-rows/WG (2 row-groups per wave,
// sequential per kv-tile) + T14 async-STAGE + T5 setprio.
//   - staging/barriers/K-V traffic HALVED per unit compute: each staged
//     64-s kv-tile now feeds both row-groups' QK^T+PV.
//   - Ps slot reused across groups (wave-private; same-wave LDS write-after-
//     read ordering already proven across kt iterations in this kernel).
//   - g=0 skips its one fully-masked tail tile (kt > 2qt+g, uniform branch).
//   - VGPR ~150-165 -> still 3 waves/SIMD (floor(512/V)); LDS 45056 -> 3
//     blocks/CU. __launch_bounds__(256,3) pins the allocator.
// ---------------------------------------------------------------------------
__global__ __launch_bounds__(256, 3) void attn_mfma(const ushort* __restrict__ QKV,
                                                    const ushort* __restrict__ Vt,
                                                    ushort* __restrict__ Yb) {
    __shared__ ushort Ks[64][136];       // [s][d]
    __shared__ ushort Vs[128][72];       // [d][s]
    __shared__ ushort Ps[4][16][72];     // per-wave P tile [qrow][s], reused per g

    const int bh = blockIdx.x;
    const int qt = (int)gridDim.y - 1 - (int)blockIdx.y;  // heavy WGs first
    const int b = bh >> 4, h = bh & 15;
    const int kvh = h >> 2;
    const int q0 = qt * 128;
    const int tid = threadIdx.x;
    const int wave = tid >> 6, lane = tid & 63;
    const int ln = lane & 15, quad = lane >> 4;

    // Q fragments for both row-groups (A-layout: m=ln, k=quad*8+j)
    short8 qf[2][4];
#pragma unroll
    for (int g = 0; g < 2; ++g) {
        const ushort* qp = QKV + ((size_t)(b * T_ + q0 + g * 64 + wave * 16 + ln)) * QKV_S + h * HD + quad * 8;
#pragma unroll
        for (int f = 0; f < 4; ++f) qf[g][f] = *(const short8*)(qp + f * 32);
    }

    // staging geometry (fixed per thread)
    const ushort* const Vbase = Vt + ((size_t)((b * NKV + kvh) * HD)) * T_;
    const ushort* const Kbase = QKV + ((size_t)(b * T_)) * QKV_S + D_ + kvh * HD;

    short8 kreg[4], vreg[4];
#define LOAD_KV(s0_)                                                        \
    do {                                                                    \
        _Pragma("unroll")                                                   \
        for (int c = 0; c < 4; ++c) {                                       \
            const int cid = tid + 256 * c;                                  \
            const int s = cid >> 4, ch = cid & 15;                          \
            kreg[c] = *(const short8*)&Kbase[((size_t)((s0_) + s)) * QKV_S + ch * 8]; \
        }                                                                   \
        _Pragma("unroll")                                                   \
        for (int c = 0; c < 4; ++c) {                                       \
            const int cid = tid + 256 * c;                                  \
            const int d = cid >> 3, ch = cid & 7;                           \
            vreg[c] = *(const short8*)&Vbase[(size_t)d * T_ + (s0_) + ch * 8]; \
        }                                                                   \
    } while (0)

    f32x4 acc[2][8];
    const f32x4 zero = {0.f, 0.f, 0.f, 0.f};
#pragma unroll
    for (int g = 0; g < 2; ++g)
#pragma unroll
        for (int j = 0; j < 8; ++j) acc[g][j] = zero;
    float m_r[2][4], l_r[2][4];
#pragma unroll
    for (int g = 0; g < 2; ++g)
#pragma unroll
        for (int r = 0; r < 4; ++r) { m_r[g][r] = -INFINITY; l_r[g][r] = 0.f; }

    const int ktmax = 2 * qt + 1;

    LOAD_KV(0);   // prologue: tile 0 into regs

    for (int kt = 0; kt <= ktmax; ++kt) {
        const int s0 = kt * 64;
        __syncthreads();   // all waves done reading Ks/Vs of previous tile
        // reg -> LDS (compiler inserts the vmcnt wait for kreg/vreg here)
#pragma unroll
        for (int c = 0; c < 4; ++c) {
            const int cid = tid + 256 * c;
            const int s = cid >> 4, ch = cid & 15;
            *(short8*)&Ks[s][ch * 8] = kreg[c];
        }
#pragma unroll
        for (int c = 0; c < 4; ++c) {
            const int cid = tid + 256 * c;
            const int d = cid >> 3, ch = cid & 7;
            *(short8*)&Vs[d][ch * 8] = vreg[c];
        }
        __syncthreads();

        // issue next tile's loads now; latency hides under compute below
        if (kt < ktmax) LOAD_KV(s0 + 64);

#pragma unroll
        for (int g = 0; g < 2; ++g) {
            if (kt > 2 * qt + g) continue;   // g=0 tail tile fully masked: skip
            const int qrow = q0 + g * 64 + wave * 16 + quad * 4;

            // S = Q K^T : 4 col-tiles of 16
            float sc[4][4];
            __builtin_amdgcn_s_setprio(1);
#pragma unroll
            for (int ct = 0; ct < 4; ++ct) {
                f32x4 s4 = zero;
#pragma unroll
                for (int f = 0; f < 4; ++f)
                    s4 = __builtin_amdgcn_mfma_f32_16x16x32_bf16(
                        qf[g][f], *(const short8*)&Ks[ct * 16 + ln][f * 32 + quad * 8], s4, 0, 0, 0);
#pragma unroll
                for (int r = 0; r < 4; ++r) sc[ct][r] = s4[r];
            }
            __builtin_amdgcn_s_setprio(0);
            // causal mask: only this group's diagonal tile needs it
            if (kt == 2 * qt + g) {
#pragma unroll
                for (int ct = 0; ct < 4; ++ct)
#pragma unroll
                    for (int r = 0; r < 4; ++r)
                        if (s0 + ct * 16 + ln > qrow + r) sc[ct][r] = -INFINITY;
            }
            // online softmax per C-layout row, exp2 domain (log2e folded in Q)
            float alpha[4];
#pragma unroll
            for (int r = 0; r < 4; ++r) {
                float mx = fmaxf(fmaxf(sc[0][r], sc[1][r]), fmaxf(sc[2][r], sc[3][r]));
                mx = fmaxf(mx, __shfl_xor(mx, 1));
                mx = fmaxf(mx, __shfl_xor(mx, 2));
                mx = fmaxf(mx, __shfl_xor(mx, 4));
                mx = fmaxf(mx, __shfl_xor(mx, 8));
                const float mnew = fmaxf(m_r[g][r], mx);
                alpha[r] = EXP2F(m_r[g][r] - mnew);
                m_r[g][r] = mnew;
#pragma unroll
                for (int ct = 0; ct < 4; ++ct) sc[ct][r] = EXP2F(sc[ct][r] - mnew);
                float sum = (sc[0][r] + sc[1][r]) + (sc[2][r] + sc[3][r]);
                sum += __shfl_xor(sum, 1);
                sum += __shfl_xor(sum, 2);
                sum += __shfl_xor(sum, 4);
                sum += __shfl_xor(sum, 8);
                l_r[g][r] = l_r[g][r] * alpha[r] + sum;
            }
            // P (C-layout) -> per-wave LDS (wave-private, no barrier needed)
#pragma unroll
            for (int ct = 0; ct < 4; ++ct)
#pragma unroll
                for (int r = 0; r < 4; ++r)
                    Ps[wave][quad * 4 + r][ct * 16 + ln] = f2b(sc[ct][r]);
            // rescale O
#pragma unroll
            for (int j = 0; j < 8; ++j)
#pragma unroll
                for (int r = 0; r < 4; ++r) acc[g][j][r] *= alpha[r];
            // P as A-fragments, two 32-wide k slices
            const short8 pa0 = *(const short8*)&Ps[wave][ln][quad * 8];
            const short8 pa1 = *(const short8*)&Ps[wave][ln][32 + quad * 8];
            __builtin_amdgcn_s_setprio(1);
#pragma unroll
            for (int j = 0; j < 8; ++j) {
                acc[g][j] = __builtin_amdgcn_mfma_f32_16x16x32_bf16(
                    pa0, *(const short8*)&Vs[j * 16 + ln][quad * 8], acc[g][j], 0, 0, 0);
                acc[g][j] = __builtin_amdgcn_mfma_f32_16x16x32_bf16(
                    pa1, *(const short8*)&Vs[j * 16 + ln][32 + quad * 8], acc[g][j], 0, 0, 0);
            }
            __builtin_amdgcn_s_setprio(0);
        }
    }
#undef LOAD_KV

#pragma unroll
    for (int g = 0; g < 2; ++g) {
        float invl[4];
#pragma unroll
        for (int r = 0; r < 4; ++r) invl[r] = 1.f / l_r[g][r];
        const int qrow = q0 + g * 64 + wave * 16 + quad * 4;
        ushort* yb = Yb + ((size_t)(b * T_ + qrow)) * D_ + h * HD + ln;
#pragma unroll
        for (int r = 0; r < 4; ++r)
#pragma unroll
            for (int j = 0; j < 8; ++j)
                yb[(size_t)r * D_ + j * 16] = f2b(acc[g][j][r] * invl[r]);
    }
}

// ---------------------------------------------------------------------------
extern "C" void kernel_launch(void* const* d_in, const int* in_sizes, int n_in,
                              void* d_out, int out_size, void* d_ws, size_t ws_size,
                              hipStream_t stream) {
    const float* x  = (const float*)d_in[0];
    const float* Wq = (const float*)d_in[1];
    const float* Wk = (const float*)d_in[2];
    const float* Wv = (const float*)d_in[3];
    const float* Wo = (const float*)d_in[4];
    float* out = (float*)d_out;

    char* w = (char*)d_ws;
    ushort* xb    = (ushort*)w;  w += (size_t)4096 * D_ * 2;       // 16.78 MB
    ushort* WqkvT = (ushort*)w;  w += (size_t)3072 * D_ * 2;       // 12.58 MB
    ushort* QKV   = (ushort*)w;  w += (size_t)4096 * QKV_S * 2;    // 20.97 MB
    ushort* Vt    = (ushort*)w;  w += (size_t)B_ * KV_D * T_ * 2;  //  4.19 MB
    ushort* Yb    = (ushort*)w;  w += (size_t)4096 * D_ * 2;       // 16.78 MB
    ushort* WoT   = (ushort*)w;  w += (size_t)D_ * D_ * 2;         //  8.39 MB
    float2* tab   = (float2*)w;  w += (size_t)T_ * 64 * 8;         //  0.52 MB

    const int M = B_ * T_;  // 4096
    dim3 blk(256);

    // all input prep (cast, 4 weight transposes, rope table) in one dispatch
    prep_all<<<11008, blk, 0, stream>>>(x, Wq, Wk, Wv, Wo, xb, WqkvT, WoT, tab);

    // fused QKV projection + rope/scale (Q,K) + V transpose epilogue
    gemm_qkv<<<dim3(3072 / 128, M / 128), blk, 0, stream>>>(xb, WqkvT, QKV, Vt, tab);

    attn_mfma<<<dim3(B_ * NH, T_ / 128), blk, 0, stream>>>(QKV, Vt, Yb);

    // output projection: bf16 Y x bf16 Wo^T -> fp32 out
    gemm_bf16<<<dim3(D_ / 128, M / 128), blk, 0, stream>>>(Yb, WoT, out, M, D_, D_);
}

// Round 10
// 273.843 us; speedup vs baseline: 1.3065x; 1.3065x over previous
//
#include <hip/hip_runtime.h>
#include <math.h>

#define B_ 4
#define T_ 1024
#define D_ 2048
#define NH 16
#define NKV 4
#define HD 128
#define KV_D 512    // NKV * HD
#define QKV_S 2560  // QKV row stride: Q (2048) + K (512); V goes only to Vt

typedef __attribute__((ext_vector_type(8))) short short8;   // 8 x bf16 (4 VGPRs)
typedef __attribute__((ext_vector_type(4))) float f32x4;    // MFMA accumulator

// fp32 -> bf16 round-to-nearest-even (finite inputs)
__device__ __forceinline__ ushort f2b(float f) {
    unsigned u = __float_as_uint(f);
    return (ushort)((u + 0x7fffu + ((u >> 16) & 1u)) >> 16);
}
__device__ __forceinline__ float b2f(ushort u) {
    return __uint_as_float((unsigned)u << 16);
}

// exp2 via v_exp_f32 (no hidden log2e multiply like __expf)
#if __has_builtin(__builtin_amdgcn_exp2f)
#define EXP2F(x) __builtin_amdgcn_exp2f(x)
#else
#define EXP2F(x) __expf((x) * 0.6931471805599453f)
#endif

#define ASYNC_COPY16(g, l)                                                  \
    __builtin_amdgcn_global_load_lds(                                       \
        (const __attribute__((address_space(1))) void*)(g),                 \
        (__attribute__((address_space(3))) void*)(l), 16, 0, 0)

#define MFMA16(ap, bp, cc) cc = __builtin_amdgcn_mfma_f32_16x16x32_bf16(ap, bp, cc, 0, 0, 0)

// ---------------------------------------------------------------------------
// prep_all (round-6 verified, vectorized transposes): 6 jobs by bid range:
//   [0,8192)       cast x fp32 -> bf16 (float4 per thread)
//   [8192,9216)    Wq -> WqkvT rows 0..2047      (64x64 vectorized transpose)
//   [9216,9472)    Wk -> WqkvT rows 2048..2559
//   [9472,9728)    Wv -> WqkvT rows 2560..3071
//   [9728,10752)   Wo -> WoT
//   [10752,11008)  rope table: tab[t*64+i] = {cos, sin}(t * 10000^(-i/64))
// ---------------------------------------------------------------------------
__global__ __launch_bounds__(256) void prep_all(const float* __restrict__ x,
                                                const float* __restrict__ Wq,
                                                const float* __restrict__ Wk,
                                                const float* __restrict__ Wv,
                                                const float* __restrict__ Wo,
                                                ushort* __restrict__ xb,
                                                ushort* __restrict__ WqkvT,
                                                ushort* __restrict__ WoT,
                                                float2* __restrict__ tab) {
    __shared__ float tile[64][65];
    const int bid = blockIdx.x;
    const int tid = threadIdx.x;
    if (bid < 8192) {                      // cast job
        const int i = bid * 256 + tid;
        const float4 v = ((const float4*)x)[i];
        ushort4 u;
        u.x = f2b(v.x); u.y = f2b(v.y); u.z = f2b(v.z); u.w = f2b(v.w);
        ((ushort4*)xb)[i] = u;
        return;
    }
    if (bid >= 10752) {                    // rope table job
        const int idx = (bid - 10752) * 256 + tid;
        const int t = idx >> 6, i = idx & 63;
        const float inv = exp2f((float)i * (-13.287712379549449f / 64.0f));
        const float ang = (float)t * inv;
        tab[idx] = make_float2(cosf(ang), sinf(ang));
        return;
    }
    // transpose jobs: W [2048][N] fp32 -> WT [N][2048] bf16, 64x64 tiles
    const float* W;
    ushort* WT;
    int N, rb;
    if (bid < 9216)      { W = Wq; WT = WqkvT;                           N = D_;   rb = bid - 8192; }
    else if (bid < 9472) { W = Wk; WT = WqkvT + (size_t)D_ * D_;         N = KV_D; rb = bid - 9216; }
    else if (bid < 9728) { W = Wv; WT = WqkvT + (size_t)(D_+KV_D) * D_;  N = KV_D; rb = bid - 9472; }
    else                 { W = Wo; WT = WoT;                             N = D_;   rb = bid - 9728; }
    const int bxn = N / 64;
    const int n0 = (rb % bxn) * 64, k0 = (rb / bxn) * 64;
    // load 64x64 floats: 16 lanes x float4 = 256 B contiguous per row
    const int tx = tid & 15, ty = tid >> 4;
#pragma unroll
    for (int i = 0; i < 4; ++i) {
        const int r = ty + i * 16;
        const float4 v = *(const float4*)&W[(size_t)(k0 + r) * N + n0 + tx * 4];
        tile[r][tx * 4 + 0] = v.x;
        tile[r][tx * 4 + 1] = v.y;
        tile[r][tx * 4 + 2] = v.z;
        tile[r][tx * 4 + 3] = v.w;
    }
    __syncthreads();
    // write: output row n = tid>>2 (4 lanes/row -> 128 B contiguous segments)
    const int n = tid >> 2, ch = (tid & 3) * 16;
    ushort tmp[16];
#pragma unroll
    for (int j = 0; j < 16; ++j) tmp[j] = f2b(tile[ch + j][n]);
    ushort* orow = WT + (size_t)(n0 + n) * D_ + k0 + ch;
    *(short8*)&orow[0] = *(short8*)&tmp[0];
    *(short8*)&orow[8] = *(short8*)&tmp[8];
}

// ---------------------------------------------------------------------------
// Fused QKV projection GEMM (round-0 verified, 76.6 us): C = xb x WqkvT^T,
// 128x128 tile, m97 K-loop (BK=32, global_load_lds width-16), per-head
// epilogue: Q/K rope via table, V transpose to Vt. LDS = 34816 B.
// ---------------------------------------------------------------------------
__global__ __launch_bounds__(256) void gemm_qkv(const ushort* __restrict__ A,
                                                const ushort* __restrict__ BT,
                                                ushort* __restrict__ QKV,
                                                ushort* __restrict__ Vt,
                                                const float2* __restrict__ tab) {
    __shared__ ushort smem[128 * 136];     // 34816 B; staging aliases the front
    ushort* As = smem;                     // 128*32 = 4096 ushorts
    ushort* Bs = smem + 4096;
    const int K = D_;
    const int tid = threadIdx.x;
    const int m0 = blockIdx.y * 128, n0 = blockIdx.x * 128;
    const int hid = n0 >> 7;               // 0..23
    const int wave = tid >> 6, lane = tid & 63;
    const int wm = (wave >> 1) * 64, wn = (wave & 1) * 64;
    const int lrow = lane & 15;
    const int quad = lane >> 4;

    f32x4 acc[4][4];
    const f32x4 zero = {0.f, 0.f, 0.f, 0.f};
#pragma unroll
    for (int i = 0; i < 4; ++i)
#pragma unroll
        for (int j = 0; j < 4; ++j) acc[i][j] = zero;

    const int srow = tid >> 2;
    const int scol = (tid & 3) * 8;
    const ushort* Ag = A + (size_t)(m0 + srow) * K + scol;
    const ushort* Bg = BT + (size_t)(n0 + srow) * K + scol;
    ushort* AsT = As + tid * 8;
    ushort* BsT = Bs + tid * 8;

    for (int k0 = 0; k0 < K; k0 += 32) {
        ASYNC_COPY16(Ag + k0, AsT);
        ASYNC_COPY16(Ag + k0 + (size_t)64 * K, AsT + 64 * 32);
        ASYNC_COPY16(Bg + k0, BsT);
        ASYNC_COPY16(Bg + k0 + (size_t)64 * K, BsT + 64 * 32);
        __syncthreads();

        short8 a[4], b[4];
#pragma unroll
        for (int mt = 0; mt < 4; ++mt)
            a[mt] = *(const short8*)&As[(wm + mt * 16 + lrow) * 32 + quad * 8];
#pragma unroll
        for (int nt = 0; nt < 4; ++nt)
            b[nt] = *(const short8*)&Bs[(wn + nt * 16 + lrow) * 32 + quad * 8];
#pragma unroll
        for (int mt = 0; mt < 4; ++mt)
#pragma unroll
            for (int nt = 0; nt < 4; ++nt)
                acc[mt][nt] = __builtin_amdgcn_mfma_f32_16x16x32_bf16(
                    a[mt], b[nt], acc[mt][nt], 0, 0, 0);
        __syncthreads();   // also guarantees staging LDS is dead -> Epi reuse
    }

    // ---- epilogue: acc (C-layout) -> bf16 LDS tile Epi[128 t][136 d-pad] ----
    ushort* Epi = smem;
#pragma unroll
    for (int mt = 0; mt < 4; ++mt)
#pragma unroll
        for (int nt = 0; nt < 4; ++nt)
#pragma unroll
            for (int r = 0; r < 4; ++r)
                Epi[(wm + mt * 16 + quad * 4 + r) * 136 + wn + nt * 16 + lrow] =
                    f2b(acc[mt][nt][r]);
    __syncthreads();

    const int b = m0 >> 10;        // batch (tile rows share one batch)
    const int t0 = m0 & 1023;

    if (hid < NH + NKV) {
        // ---- Q or K head: rope from table, write to QKV ----
        const bool isQ = hid < NH;
        const size_t colbase = isQ ? hid * HD : (size_t)D_ + (hid - NH) * HD;
        // Q scale: 1/sqrt(128) * log2(e) (softmax runs in exp2 domain)
        const float sc = isQ ? (0.08838834764831845f * 1.4426950408889634f) : 1.0f;
        const int r = tid >> 1;            // local t row 0..127
        const int hf = tid & 1;            // d-half group: d in [hf*32, hf*32+32)
        const int t = t0 + r;
        ushort* orow = QKV + (size_t)(m0 + r) * QKV_S + colbase;
        const float4* tab4 = (const float4*)tab;   // 2 (cos,sin) pairs per float4
#pragma unroll
        for (int jj = 0; jj < 4; ++jj) {
            const int dbase = hf * 32 + jj * 8;
            const short8 lo = *(const short8*)&Epi[r * 136 + dbase];
            const short8 hi = *(const short8*)&Epi[r * 136 + 64 + dbase];
            ushort olo[8], ohi[8];
#pragma unroll
            for (int k = 0; k < 4; ++k) {
                const float4 cs = tab4[((t * 64 + dbase) >> 1) + k];
                const float x1a = b2f(lo[2 * k]),     x2a = b2f(hi[2 * k]);
                const float x1b = b2f(lo[2 * k + 1]), x2b = b2f(hi[2 * k + 1]);
                olo[2 * k]     = f2b((x1a * cs.x - x2a * cs.y) * sc);
                ohi[2 * k]     = f2b((x2a * cs.x + x1a * cs.y) * sc);
                olo[2 * k + 1] = f2b((x1b * cs.z - x2b * cs.w) * sc);
                ohi[2 * k + 1] = f2b((x2b * cs.z + x1b * cs.w) * sc);
            }
            *(short8*)&orow[dbase]      = *(short8*)olo;
            *(short8*)&orow[dbase + 64] = *(short8*)ohi;
        }
    } else {
        // ---- V head: transpose Epi[t][d] -> Vt[(b*NKV+kv)*HD + d][t] ----
        const int kv = hid - (NH + NKV);
        const int d = tid & 127;           // conflict-free column reads (2-way)
        const int hf = tid >> 7;           // t-half: [hf*64, hf*64+64)
        ushort* vrow = Vt + ((size_t)((b * NKV + kv) * HD + d)) * T_ + t0 + hf * 64;
#pragma unroll
        for (int jj = 0; jj < 8; ++jj) {
            ushort pk[8];
#pragma unroll
            for (int k = 0; k < 8; ++k)
                pk[k] = Epi[(hf * 64 + jj * 8 + k) * 136 + d];
            *(short8*)&vrow[jj * 8] = *(short8*)pk;
        }
    }
}

// ---------------------------------------------------------------------------
// Output-projection GEMM (round-8 verified): BK=64 + swizzle variant.
// C[M,N] fp32 = A[M,K] bf16 x BT[N,K] bf16.
// ---------------------------------------------------------------------------
__global__ __launch_bounds__(256) void gemm_bf16(const ushort* __restrict__ A,
                                                 const ushort* __restrict__ BT,
                                                 float* __restrict__ C,
                                                 int M, int N, int K) {
    __shared__ ushort As[128 * 64];
    __shared__ ushort Bs[128 * 64];
    const int tid = threadIdx.x;
    const int m0 = blockIdx.y * 128, n0 = blockIdx.x * 128;
    const int wave = tid >> 6, lane = tid & 63;
    const int wm = (wave >> 1) * 64, wn = (wave & 1) * 64;
    const int lrow = lane & 15;
    const int quad = lane >> 4;

    f32x4 acc[4][4];
    const f32x4 zero = {0.f, 0.f, 0.f, 0.f};
#pragma unroll
    for (int i = 0; i < 4; ++i)
#pragma unroll
        for (int j = 0; j < 4; ++j) acc[i][j] = zero;

    const int srow = tid >> 3;
    const int scol = ((tid & 7) * 8) ^ ((srow & 7) << 3);   // pre-swizzled src col
    const ushort* Ag = A + (size_t)(m0 + srow) * K + scol;
    const ushort* Bg = BT + (size_t)(n0 + srow) * K + scol;
    ushort* AsT = As + tid * 8;
    ushort* BsT = Bs + tid * 8;
    const int swr = (lrow & 7) << 3;       // read-side un-swizzle

    for (int k0 = 0; k0 < K; k0 += 64) {
#pragma unroll
        for (int c = 0; c < 4; ++c) {
            ASYNC_COPY16(Ag + k0 + (size_t)(c * 32) * K, AsT + c * 2048);
            ASYNC_COPY16(Bg + k0 + (size_t)(c * 32) * K, BsT + c * 2048);
        }
        __syncthreads();

#pragma unroll
        for (int ks = 0; ks < 2; ++ks) {
            const int col = (quad * 8) ^ (ks * 32) ^ swr;
            short8 a[4], b[4];
#pragma unroll
            for (int mt = 0; mt < 4; ++mt)
                a[mt] = *(const short8*)&As[(wm + mt * 16 + lrow) * 64 + col];
#pragma unroll
            for (int nt = 0; nt < 4; ++nt)
                b[nt] = *(const short8*)&Bs[(wn + nt * 16 + lrow) * 64 + col];
#pragma unroll
            for (int mt = 0; mt < 4; ++mt)
#pragma unroll
                for (int nt = 0; nt < 4; ++nt)
                    MFMA16(a[mt], b[nt], acc[mt][nt]);
        }
        __syncthreads();
    }

    const int crow = quad * 4;
    const int ccol = lrow;
#pragma unroll
    for (int mt = 0; mt < 4; ++mt)
#pragma unroll
        for (int nt = 0; nt < 4; ++nt)
#pragma unroll
            for (int r = 0; r < 4; ++r)
                C[(size_t)(m0 + wm + mt * 16 + crow + r) * N +
                  n0 + wn + nt * 16 + ccol] = acc[mt][nt][r];
}

// ---------------------------------------------------------------------------
// MFMA flash attention (round-8 structure restored: 64 q-rows/WG, T14
// async-STAGE, VGPR 84, no spills) + round-10 T5 setprio around the two
// MFMA clusters (the only delta vs round-8; m191: +4-7% on attn with
// independent-phase blocks — 3 blocks/CU here run at different kt).
// ---------------------------------------------------------------------------
__global__ __launch_bounds__(256) void attn_mfma(const ushort* __restrict__ QKV,
                                                 const ushort* __restrict__ Vt,
                                                 ushort* __restrict__ Yb) {
    __shared__ ushort Ks[64][136];       // [s][d]
    __shared__ ushort Vs[128][72];       // [d][s]
    __shared__ ushort Ps[4][16][72];     // per-wave P tile [qrow][s]

    const int bh = blockIdx.x;
    const int qt = (int)gridDim.y - 1 - (int)blockIdx.y;  // heavy WGs first
    const int b = bh >> 4, h = bh & 15;
    const int kvh = h >> 2;
    const int q0 = qt * 64;
    const int tid = threadIdx.x;
    const int wave = tid >> 6, lane = tid & 63;
    const int ln = lane & 15, quad = lane >> 4;

    // Q fragments (A-layout: m=ln, k=quad*8+j), rows q0 + wave*16 + ln
    short8 qf[4];
    {
        const ushort* qp = QKV + ((size_t)(b * T_ + q0 + wave * 16 + ln)) * QKV_S + h * HD + quad * 8;
#pragma unroll
        for (int f = 0; f < 4; ++f) qf[f] = *(const short8*)(qp + f * 32);
    }

    // staging geometry (fixed per thread)
    const size_t kv_row = (size_t)((b * NKV + kvh) * HD);
    const ushort* const Vbase = Vt + kv_row * T_;
    const ushort* const Kbase = QKV + ((size_t)(b * T_)) * QKV_S + D_ + kvh * HD;

    short8 kreg[4], vreg[4];
#define LOAD_KV(s0_)                                                        \
    do {                                                                    \
        _Pragma("unroll")                                                   \
        for (int c = 0; c < 4; ++c) {                                       \
            const int cid = tid + 256 * c;                                  \
            const int s = cid >> 4, ch = cid & 15;                          \
            kreg[c] = *(const short8*)&Kbase[((size_t)((s0_) + s)) * QKV_S + ch * 8]; \
        }                                                                   \
        _Pragma("unroll")                                                   \
        for (int c = 0; c < 4; ++c) {                                       \
            const int cid = tid + 256 * c;                                  \
            const int d = cid >> 3, ch = cid & 7;                           \
            vreg[c] = *(const short8*)&Vbase[(size_t)d * T_ + (s0_) + ch * 8]; \
        }                                                                   \
    } while (0)

    f32x4 acc[8];
    const f32x4 zero = {0.f, 0.f, 0.f, 0.f};
#pragma unroll
    for (int j = 0; j < 8; ++j) acc[j] = zero;
    float m_r[4], l_r[4];
#pragma unroll
    for (int r = 0; r < 4; ++r) { m_r[r] = -INFINITY; l_r[r] = 0.f; }

    const int qrow = q0 + wave * 16 + quad * 4;   // C-layout row base (+r)

    LOAD_KV(0);   // prologue: tile 0 into regs

    for (int kt = 0; kt <= qt; ++kt) {
        const int s0 = kt * 64;
        __syncthreads();   // all waves done reading Ks/Vs of previous tile
        // reg -> LDS (compiler inserts the vmcnt wait for kreg/vreg here)
#pragma unroll
        for (int c = 0; c < 4; ++c) {
            const int cid = tid + 256 * c;
            const int s = cid >> 4, ch = cid & 15;
            *(short8*)&Ks[s][ch * 8] = kreg[c];
        }
#pragma unroll
        for (int c = 0; c < 4; ++c) {
            const int cid = tid + 256 * c;
            const int d = cid >> 3, ch = cid & 7;
            *(short8*)&Vs[d][ch * 8] = vreg[c];
        }
        __syncthreads();

        // issue next tile's loads now; latency hides under compute below
        if (kt < qt) LOAD_KV(s0 + 64);

        // S = Q K^T : 4 col-tiles of 16
        float sc[4][4];
        __builtin_amdgcn_s_setprio(1);
#pragma unroll
        for (int ct = 0; ct < 4; ++ct) {
            f32x4 s4 = zero;
#pragma unroll
            for (int f = 0; f < 4; ++f)
                s4 = __builtin_amdgcn_mfma_f32_16x16x32_bf16(
                    qf[f], *(const short8*)&Ks[ct * 16 + ln][f * 32 + quad * 8], s4, 0, 0, 0);
#pragma unroll
            for (int r = 0; r < 4; ++r) sc[ct][r] = s4[r];
        }
        __builtin_amdgcn_s_setprio(0);
        // causal mask: only the diagonal tile needs it
        if (kt == qt) {
#pragma unroll
            for (int ct = 0; ct < 4; ++ct)
#pragma unroll
                for (int r = 0; r < 4; ++r)
                    if (s0 + ct * 16 + ln > qrow + r) sc[ct][r] = -INFINITY;
        }
        // online softmax per C-layout row, exp2 domain (log2e folded into Q)
        float alpha[4];
#pragma unroll
        for (int r = 0; r < 4; ++r) {
            float mx = fmaxf(fmaxf(sc[0][r], sc[1][r]), fmaxf(sc[2][r], sc[3][r]));
            mx = fmaxf(mx, __shfl_xor(mx, 1));
            mx = fmaxf(mx, __shfl_xor(mx, 2));
            mx = fmaxf(mx, __shfl_xor(mx, 4));
            mx = fmaxf(mx, __shfl_xor(mx, 8));
            const float mnew = fmaxf(m_r[r], mx);
            alpha[r] = EXP2F(m_r[r] - mnew);
            m_r[r] = mnew;
#pragma unroll
            for (int ct = 0; ct < 4; ++ct) sc[ct][r] = EXP2F(sc[ct][r] - mnew);
            float sum = (sc[0][r] + sc[1][r]) + (sc[2][r] + sc[3][r]);
            sum += __shfl_xor(sum, 1);
            sum += __shfl_xor(sum, 2);
            sum += __shfl_xor(sum, 4);
            sum += __shfl_xor(sum, 8);
            l_r[r] = l_r[r] * alpha[r] + sum;
        }
        // P (C-layout) -> per-wave LDS (wave-private, no barrier needed)
#pragma unroll
        for (int ct = 0; ct < 4; ++ct)
#pragma unroll
            for (int r = 0; r < 4; ++r)
                Ps[wave][quad * 4 + r][ct * 16 + ln] = f2b(sc[ct][r]);
        // rescale O
#pragma unroll
        for (int j = 0; j < 8; ++j)
#pragma unroll
            for (int r = 0; r < 4; ++r) acc[j][r] *= alpha[r];
        // P as A-fragments, two 32-wide k slices
        const short8 pa0 = *(const short8*)&Ps[wave][ln][quad * 8];
        const short8 pa1 = *(const short8*)&Ps[wave][ln][32 + quad * 8];
        __builtin_amdgcn_s_setprio(1);
#pragma unroll
        for (int j = 0; j < 8; ++j) {
            acc[j] = __builtin_amdgcn_mfma_f32_16x16x32_bf16(
                pa0, *(const short8*)&Vs[j * 16 + ln][quad * 8], acc[j], 0, 0, 0);
            acc[j] = __builtin_amdgcn_mfma_f32_16x16x32_bf16(
                pa1, *(const short8*)&Vs[j * 16 + ln][32 + quad * 8], acc[j], 0, 0, 0);
        }
        __builtin_amdgcn_s_setprio(0);
    }
#undef LOAD_KV

    float invl[4];
#pragma unroll
    for (int r = 0; r < 4; ++r) invl[r] = 1.f / l_r[r];
    ushort* yb = Yb + ((size_t)(b * T_ + qrow)) * D_ + h * HD + ln;
#pragma unroll
    for (int r = 0; r < 4; ++r)
#pragma unroll
        for (int j = 0; j < 8; ++j)
            yb[(size_t)r * D_ + j * 16] = f2b(acc[j][r] * invl[r]);
}

// ---------------------------------------------------------------------------
extern "C" void kernel_launch(void* const* d_in, const int* in_sizes, int n_in,
                              void* d_out, int out_size, void* d_ws, size_t ws_size,
                              hipStream_t stream) {
    const float* x  = (const float*)d_in[0];
    const float* Wq = (const float*)d_in[1];
    const float* Wk = (const float*)d_in[2];
    const float* Wv = (const float*)d_in[3];
    const float* Wo = (const float*)d_in[4];
    float* out = (float*)d_out;

    char* w = (char*)d_ws;
    ushort* xb    = (ushort*)w;  w += (size_t)4096 * D_ * 2;       // 16.78 MB
    ushort* WqkvT = (ushort*)w;  w += (size_t)3072 * D_ * 2;       // 12.58 MB
    ushort* QKV   = (ushort*)w;  w += (size_t)4096 * QKV_S * 2;    // 20.97 MB
    ushort* Vt    = (ushort*)w;  w += (size_t)B_ * KV_D * T_ * 2;  //  4.19 MB
    ushort* Yb    = (ushort*)w;  w += (size_t)4096 * D_ * 2;       // 16.78 MB
    ushort* WoT   = (ushort*)w;  w += (size_t)D_ * D_ * 2;         //  8.39 MB
    float2* tab   = (float2*)w;  w += (size_t)T_ * 64 * 8;         //  0.52 MB

    const int M = B_ * T_;  // 4096
    dim3 blk(256);

    // all input prep (cast, 4 weight transposes, rope table) in one dispatch
    prep_all<<<11008, blk, 0, stream>>>(x, Wq, Wk, Wv, Wo, xb, WqkvT, WoT, tab);

    // fused QKV projection + rope/scale (Q,K) + V transpose epilogue
    gemm_qkv<<<dim3(3072 / 128, M / 128), blk, 0, stream>>>(xb, WqkvT, QKV, Vt, tab);

    attn_mfma<<<dim3(B_ * NH, T_ / 64), blk, 0, stream>>>(QKV, Vt, Yb);

    // output projection: bf16 Y x bf16 Wo^T -> fp32 out
    gemm_bf16<<<dim3(D_ / 128, M / 128), blk, 0, stream>>>(Yb, WoT, out, M, D_, D_);
}